// Round 8
// baseline (427.813 us; speedup 1.0000x reference)
//
#include <hip/hip_runtime.h>

// ---------------------------------------------------------------------------
// 2-layer GCN on MI355X.  Pipeline (12 launches):
//   wprep(W1) -> wprep(W2) -> init(+dtype detect) -> count -> scan1/2/3
//   -> fill CSR (src only) -> GEMM1 (MFMA split-bf16, out tiled, x dinv)
//   -> AGG1 (ft-tiled passes, L2-resident slice) -> GEMM2 (tiled in/out)
//   -> AGG2 (ft-tiled) -> d_out
// Round-2: agg MLP restructure (537->413).  Round-4: device-wide scan
//   (413->338).  Round-5: split-bf16 MFMA GEMMs (338->303).
// Round-6: feature-tiled aggregation.  H stored [ft][N][16] so each pass's
//   random gather works in a 3.2MB slice (< 4MB per-XCD L2); dinv[src]
//   folded into GEMM epilogue so edge meta = bare src int.  agg1 was 59us
//   at 46% HBM from L2-missing 512B gathers.
// Round-7/8: resubmits (round-6 GPU-acquisition timeout, round-7 container
//   failure -- both infra; same source passed cleanly after round-2's
//   identical infra error).
// ---------------------------------------------------------------------------

typedef __attribute__((ext_vector_type(8))) short bf16x8;
typedef __attribute__((ext_vector_type(4))) float f32x4;

__device__ __forceinline__ unsigned short f2bf_rne(float f) {
    unsigned u = __float_as_uint(f);
    u = u + 0x7fffu + ((u >> 16) & 1u);          // round-to-nearest-even
    return (unsigned short)(u >> 16);
}

// One-time W transform: W[K][N] fp32 -> Wt_hi/Wt_lo[N][K] bf16 (hi + residual).
__global__ void k_wprep(const float* __restrict__ W, unsigned short* __restrict__ Wt_hi,
                        unsigned short* __restrict__ Wt_lo, int K, int N) {
    int id = blockIdx.x * blockDim.x + threadIdx.x;
    if (id < K * N) {
        int k = id / N, nn = id - k * N;         // coalesced read of W
        float f = W[id];
        unsigned short h = f2bf_rne(f);
        float hf = __uint_as_float((unsigned)h << 16);
        Wt_hi[(size_t)nn * K + k] = h;
        Wt_lo[(size_t)nn * K + k] = f2bf_rne(f - hf);
    }
}

// init: zero cnt; block 0 wave 0 also detects int64-vs-int32 edge layout.
__global__ void k_init(const int* __restrict__ e32, int* __restrict__ flag,
                       int* __restrict__ cnt, int n) {
    int i = blockIdx.x * blockDim.x + threadIdx.x;
    if (i < n) cnt[i] = 0;
    if (blockIdx.x == 0 && threadIdx.x < 64) {
        int v = e32[2 * threadIdx.x + 1];
        unsigned long long ball = __ballot(v == 0);
        if (threadIdx.x == 0) flag[0] = (ball == ~0ull) ? 1 : 0;
    }
}

__device__ __forceinline__ int edge_at(const int* __restrict__ e32, long long idx, int is64) {
    return is64 ? e32[2 * idx] : e32[(int)idx];
}

__global__ void k_count(const int* __restrict__ e32, const int* __restrict__ flag,
                        int* __restrict__ cnt, int E) {
    int is64 = flag[0];
    int e = blockIdx.x * blockDim.x + threadIdx.x;
    if (e < E) {
        int d = edge_at(e32, (long long)E + e, is64);   // dst row = second half
        atomicAdd(&cnt[d], 1);
    }
}

#define SCB 256            // scan block threads
#define SCE 8              // elements per thread
#define SCTILE (SCB * SCE) // 2048 elements per block

__global__ __launch_bounds__(SCB) void k_scan1(const int* __restrict__ cnt,
                                               int* __restrict__ blksum, int n) {
    __shared__ int red[SCB];
    int t = threadIdx.x;
    int base = blockIdx.x * SCTILE + t * SCE;
    int s = 0;
    if (base + SCE <= n) {
        int4 a = *reinterpret_cast<const int4*>(&cnt[base]);
        int4 b = *reinterpret_cast<const int4*>(&cnt[base + 4]);
        s = a.x + a.y + a.z + a.w + b.x + b.y + b.z + b.w;
    } else {
        for (int i = 0; i < SCE; ++i) { int idx = base + i; if (idx < n) s += cnt[idx]; }
    }
    red[t] = s;
    __syncthreads();
    for (int off = SCB / 2; off > 0; off >>= 1) {
        if (t < off) red[t] += red[t + off];
        __syncthreads();
    }
    if (t == 0) blksum[blockIdx.x] = red[0];
}

__global__ __launch_bounds__(SCB) void k_scan2(int* __restrict__ blksum, int nb) {
    __shared__ int red[SCB];
    int t = threadIdx.x;
    int v = (t < nb) ? blksum[t] : 0;
    red[t] = v;
    __syncthreads();
    for (int off = 1; off < SCB; off <<= 1) {          // Hillis-Steele inclusive
        int x = (t >= off) ? red[t - off] : 0;
        __syncthreads();
        red[t] += x;
        __syncthreads();
    }
    if (t < nb) blksum[t] = red[t] - v;                // exclusive, in place
}

// scan3: rowptr + fused dinv + cursor zero.
__global__ __launch_bounds__(SCB) void k_scan3(const int* __restrict__ cnt,
                                               const int* __restrict__ blksum,
                                               int* __restrict__ rowptr,
                                               float* __restrict__ dinv,
                                               int* __restrict__ cursor,
                                               int n, int E) {
    __shared__ int red[SCB];
    int t = threadIdx.x;
    int base = blockIdx.x * SCTILE + t * SCE;
    int v[SCE];
    int s = 0;
    if (base + SCE <= n) {
        int4 a = *reinterpret_cast<const int4*>(&cnt[base]);
        int4 b = *reinterpret_cast<const int4*>(&cnt[base + 4]);
        v[0] = a.x; v[1] = a.y; v[2] = a.z; v[3] = a.w;
        v[4] = b.x; v[5] = b.y; v[6] = b.z; v[7] = b.w;
        s = v[0] + v[1] + v[2] + v[3] + v[4] + v[5] + v[6] + v[7];
    } else {
        for (int i = 0; i < SCE; ++i) {
            int idx = base + i;
            v[i] = (idx < n) ? cnt[idx] : 0;
            s += v[i];
        }
    }
    red[t] = s;
    __syncthreads();
    for (int off = 1; off < SCB; off <<= 1) {
        int x = (t >= off) ? red[t - off] : 0;
        __syncthreads();
        red[t] += x;
        __syncthreads();
    }
    int run = red[t] - s + blksum[blockIdx.x];
    #pragma unroll
    for (int i = 0; i < SCE; ++i) {
        int idx = base + i;
        if (idx < n) {
            rowptr[idx] = run;
            dinv[idx]   = rsqrtf(1.0f + (float)v[i]);  // self-loop included
            cursor[idx] = 0;
            run += v[i];
        }
    }
    if (blockIdx.x == 0 && t == 0) rowptr[n] = E;
}

// CSR fill: esrc[pos] = src   (dinv folded into H rows, no per-edge norm).
__global__ void k_fill(const int* __restrict__ e32, const int* __restrict__ flag,
                       const int* __restrict__ rowptr, int* __restrict__ cursor,
                       int* __restrict__ esrc, int E) {
    int is64 = flag[0];
    int e = blockIdx.x * blockDim.x + threadIdx.x;
    if (e < E) {
        int s = edge_at(e32, e, is64);
        int d = edge_at(e32, (long long)E + e, is64);
        int pos = rowptr[d] + atomicAdd(&cursor[d], 1);
        esrc[pos] = s;
    }
}

// Split-bf16 MFMA GEMM:  Ht[ft][n][16] = dinv ⊙ (A @ W)   (output always tiled).
// A row-major [n][K] (IN_TILED=false) or tiled [K/16][n][16] (IN_TILED=true).
// BM=64, 4 waves; wave w owns rows w*16..w*16+15 x all N cols.
// m89-verified 16x16x32 layouts: a[j]=A[l&15][(l>>4)*8+j], b[j]=B[(l>>4)*8+j][l&15],
// d[i]=D[(l>>4)*4+i][l&15].
template<int K, int N, bool IN_TILED>
__global__ __launch_bounds__(256) void k_gemm_mfma(const float* __restrict__ A,
        const unsigned short* __restrict__ Wt_hi, const unsigned short* __restrict__ Wt_lo,
        const float* __restrict__ dinv, float* __restrict__ H, int n) {
    constexpr int NT  = N / 16;     // n-tiles per wave
    constexpr int LDA = 40;         // padded LDS row stride in bf16 (80 B, <=2-way conflicts)
    __shared__ unsigned short Ah[64 * LDA], Al[64 * LDA];
    __shared__ unsigned short Wh[N * LDA],  Wl[N * LDA];
    int t = threadIdx.x;
    int w = t >> 6, l = t & 63;
    int row0 = blockIdx.x * 64;
    int lrow = l & 15, lk = (l >> 4) * 8;
    f32x4 acc[NT];
    #pragma unroll
    for (int i = 0; i < NT; ++i) acc[i] = (f32x4){0.f, 0.f, 0.f, 0.f};

    for (int k0 = 0; k0 < K; k0 += 32) {
        {   // stage A tile [64][32] fp32 -> hi/lo bf16; thread t: row t>>2, k (t&3)*8
            int r = t >> 2, kk = (t & 3) * 8;
            int grow = row0 + r;
            float v[8] = {0.f, 0.f, 0.f, 0.f, 0.f, 0.f, 0.f, 0.f};
            if (grow < n) {
                float4 x0, x1;
                if (IN_TILED) {
                    int kg = k0 + kk;
                    const float* base = &A[((size_t)(kg >> 4) * n + grow) * 16 + (kg & 15)];
                    x0 = *reinterpret_cast<const float4*>(base);
                    x1 = *reinterpret_cast<const float4*>(base + 4);
                } else {
                    x0 = *reinterpret_cast<const float4*>(&A[(size_t)grow * K + k0 + kk]);
                    x1 = *reinterpret_cast<const float4*>(&A[(size_t)grow * K + k0 + kk + 4]);
                }
                v[0] = x0.x; v[1] = x0.y; v[2] = x0.z; v[3] = x0.w;
                v[4] = x1.x; v[5] = x1.y; v[6] = x1.z; v[7] = x1.w;
            }
            unsigned short h8[8], l8[8];
            #pragma unroll
            for (int i = 0; i < 8; ++i) {
                unsigned short h = f2bf_rne(v[i]);
                h8[i] = h;
                l8[i] = f2bf_rne(v[i] - __uint_as_float((unsigned)h << 16));
            }
            *reinterpret_cast<bf16x8*>(&Ah[r * LDA + kk]) = *reinterpret_cast<const bf16x8*>(h8);
            *reinterpret_cast<bf16x8*>(&Al[r * LDA + kk]) = *reinterpret_cast<const bf16x8*>(l8);
        }
        // stage W k-slice: Wt[nn][k0..k0+32] -> Wh/Wl, 16B chunks
        for (int c = t; c < N * 4; c += 256) {
            int nn = c >> 2, part = (c & 3) * 8;
            *reinterpret_cast<bf16x8*>(&Wh[nn * LDA + part]) =
                *reinterpret_cast<const bf16x8*>(&Wt_hi[(size_t)nn * K + k0 + part]);
            *reinterpret_cast<bf16x8*>(&Wl[nn * LDA + part]) =
                *reinterpret_cast<const bf16x8*>(&Wt_lo[(size_t)nn * K + k0 + part]);
        }
        __syncthreads();
        bf16x8 ah = *reinterpret_cast<const bf16x8*>(&Ah[(w * 16 + lrow) * LDA + lk]);
        bf16x8 al = *reinterpret_cast<const bf16x8*>(&Al[(w * 16 + lrow) * LDA + lk]);
        #pragma unroll
        for (int tt = 0; tt < NT; ++tt) {
            bf16x8 bh = *reinterpret_cast<const bf16x8*>(&Wh[(tt * 16 + lrow) * LDA + lk]);
            bf16x8 bl = *reinterpret_cast<const bf16x8*>(&Wl[(tt * 16 + lrow) * LDA + lk]);
            acc[tt] = __builtin_amdgcn_mfma_f32_16x16x32_bf16(ah, bh, acc[tt], 0, 0, 0);
            acc[tt] = __builtin_amdgcn_mfma_f32_16x16x32_bf16(al, bh, acc[tt], 0, 0, 0);
            acc[tt] = __builtin_amdgcn_mfma_f32_16x16x32_bf16(ah, bl, acc[tt], 0, 0, 0);
        }
        __syncthreads();
    }
    #pragma unroll
    for (int i = 0; i < 4; ++i) {
        int grow = row0 + w * 16 + (l >> 4) * 4 + i;
        if (grow < n) {
            float dv = dinv[grow];
            #pragma unroll
            for (int tt = 0; tt < NT; ++tt)
                H[((size_t)tt * n + grow) * 16 + lrow] = acc[tt][i] * dv;
        }
    }
}

// Feature-tiled aggregation.  One pass per 16-feature slice Hf=[n][16] (3.2MB,
// fits per-XCD L2).  ft-major 1-D grid so co-resident blocks share one slice.
// Wave = 1 node: lanes = 4 edge-slots x 16 features; shfl_xor(16,32) reduce.
// out = acc*dinv[node] + bias  (acc includes self term; src dinv pre-folded).
template<bool RELU, bool OUT_TILED>
__global__ __launch_bounds__(256) void k_aggt(const float* __restrict__ Ht,
                                              const float* __restrict__ dinv,
                                              const int* __restrict__ rowptr,
                                              const int* __restrict__ esrc,
                                              const float* __restrict__ bias,
                                              float* __restrict__ O,
                                              int n, int xblocks, int nf) {
    int ft = blockIdx.x / xblocks;
    int xb = blockIdx.x - ft * xblocks;
    int w = threadIdx.x >> 6, lane = threadIdx.x & 63;
    int sub = lane >> 4, fi = lane & 15;
    const float* __restrict__ Hf = Ht + (size_t)ft * n * 16;
    float bv = bias[ft * 16 + fi];
    #pragma unroll
    for (int i = 0; i < 4; ++i) {
        int node = xb * 16 + i * 4 + w;
        if (node >= n) break;                    // wave-uniform
        int lo = rowptr[node], hi = rowptr[node + 1];
        float acc = (sub == 0) ? Hf[(size_t)node * 16 + fi] : 0.f;  // self term
        int e = lo + sub;
        while (e + 4 < hi) {                     // 2-deep unroll, stride 4
            int s0 = esrc[e], s1 = esrc[e + 4];
            float v0 = Hf[(size_t)s0 * 16 + fi];
            float v1 = Hf[(size_t)s1 * 16 + fi];
            acc += v0 + v1;
            e += 8;
        }
        if (e < hi) acc += Hf[(size_t)esrc[e] * 16 + fi];
        acc += __shfl_xor(acc, 16);
        acc += __shfl_xor(acc, 32);
        if (lane < 16) {
            float r = acc * dinv[node] + bv;
            if (RELU) r = fmaxf(r, 0.f);
            if (OUT_TILED) O[((size_t)ft * n + node) * 16 + fi] = r;
            else           O[(size_t)node * nf + ft * 16 + fi]  = r;
        }
    }
}

extern "C" void kernel_launch(void* const* d_in, const int* in_sizes, int n_in,
                              void* d_out, int out_size, void* d_ws, size_t ws_size,
                              hipStream_t stream) {
    const float* x   = (const float*)d_in[0];
    const int*   e32 = (const int*)d_in[1];
    const float* W1  = (const float*)d_in[2];
    const float* b1  = (const float*)d_in[3];
    const float* W2  = (const float*)d_in[4];
    const float* b2  = (const float*)d_in[5];
    float* out = (float*)d_out;

    const int HID  = in_sizes[3];           // 128
    const int FIN  = in_sizes[2] / HID;     // 256
    const int N    = in_sizes[0] / FIN;     // 50000
    const int E    = in_sizes[1] / 2;       // 800000
    const int OUT  = in_sizes[5];           // 64
    (void)n_in; (void)out_size; (void)ws_size;

    char* ws = (char*)d_ws;
    size_t off = 0;
    auto take = [&](size_t bytes) -> void* {
        void* p = ws + off;
        off += (bytes + 255) & ~(size_t)255;
        return p;
    };
    int*            flag   = (int*)            take(4);
    float*          dinv   = (float*)          take((size_t)N * 4);
    int*            cnt    = (int*)            take((size_t)N * 4);
    int*            rowptr = (int*)            take((size_t)(N + 1) * 4);
    int*            blksum = (int*)            take((size_t)SCB * 4);
    unsigned short* w1h    = (unsigned short*) take((size_t)FIN * HID * 2);
    unsigned short* w1l    = (unsigned short*) take((size_t)FIN * HID * 2);
    unsigned short* w2h    = (unsigned short*) take((size_t)HID * OUT * 2);
    unsigned short* w2l    = (unsigned short*) take((size_t)HID * OUT * 2);
    int*            esrc   = (int*)            take((size_t)E * 4);
    float*          h1t    = (float*)          take((size_t)N * HID * 4);
    float*          agg1t  = (float*)          take((size_t)N * HID * 4);
    float*          h2t    = h1t;  // h1t dead after AGG1; reuse for layer-2 transform

    int gN  = (N + 255) / 256;
    int gE  = (E + 255) / 256;
    int gS  = (N + SCTILE - 1) / SCTILE;    // 25 @ N=50000
    int gM  = (N + 63) / 64;                // 782
    int gW1 = (FIN * HID + 255) / 256;
    int gW2 = (HID * OUT + 255) / 256;
    int XB  = (N + 15) / 16;                // agg x-blocks (16 nodes each)
    int gA1 = XB * (HID / 16);              // ft-major passes
    int gA2 = XB * (OUT / 16);

    k_wprep <<<gW1, 256, 0, stream>>>(W1, w1h, w1l, FIN, HID);
    k_wprep <<<gW2, 256, 0, stream>>>(W2, w2h, w2l, HID, OUT);
    k_init  <<<gN,  256, 0, stream>>>(e32, flag, cnt, N);
    k_count <<<gE,  256, 0, stream>>>(e32, flag, cnt, E);
    k_scan1 <<<gS,  SCB, 0, stream>>>(cnt, blksum, N);
    k_scan2 <<<1,   SCB, 0, stream>>>(blksum, gS);
    k_scan3 <<<gS,  SCB, 0, stream>>>(cnt, blksum, rowptr, dinv, cnt, N, E);
    k_fill  <<<gE,  256, 0, stream>>>(e32, flag, rowptr, cnt, esrc, E);
    k_gemm_mfma<256, 128, false><<<gM, 256, 0, stream>>>(x, w1h, w1l, dinv, h1t, N);
    k_aggt<true,  true > <<<gA1, 256, 0, stream>>>(h1t, dinv, rowptr, esrc, b1, agg1t, N, XB, HID);
    k_gemm_mfma<128, 64, true> <<<gM, 256, 0, stream>>>(agg1t, w2h, w2l, dinv, h2t, N);
    k_aggt<false, false> <<<gA2, 256, 0, stream>>>(h2t, dinv, rowptr, esrc, b2, out, N, XB, OUT);
}

// Round 9
// 271.081 us; speedup vs baseline: 1.5782x; 1.5782x over previous
//
#include <hip/hip_runtime.h>

// ---------------------------------------------------------------------------
// 2-layer GCN on MI355X.  Pipeline (12 launches):
//   wprep(W1) -> wprep(W2) -> init(+dtype detect) -> count -> scan1/2/3
//   -> fill CSR (src only) -> GEMM1 (MFMA split-bf16, epilogue: xdinv, bf16
//   table) -> AGG1 (bf16 gather, fp32 out) -> GEMM2 -> AGG2 -> d_out
// Round-2: agg MLP restructure (537->413).  Round-4: device-wide scan
//   (413->338).  Round-5: split-bf16 MFMA GEMMs (338->303).
// Round-8 FAILED: ft-tiled agg regressed 59->137us (slice replicates into
//   all 8 XCD L2s -> no HBM saving; 8x request count; latency-bound).
// Round-9: revert to round-5 agg structure (node per half/quarter-wave,
//   whole-row gathers) + bf16 gather tables (410->205MB, 205->102MB) +
//   8-deep edge unroll.  dinv folded in GEMM epilogue; edge meta = 4B src.
// ---------------------------------------------------------------------------

typedef __attribute__((ext_vector_type(8))) short bf16x8;
typedef __attribute__((ext_vector_type(4))) float f32x4;

__device__ __forceinline__ unsigned short f2bf_rne(float f) {
    unsigned u = __float_as_uint(f);
    u = u + 0x7fffu + ((u >> 16) & 1u);          // round-to-nearest-even
    return (unsigned short)(u >> 16);
}

__device__ __forceinline__ float4 bf4f(ushort4 u) {
    float4 r;
    r.x = __uint_as_float((unsigned)u.x << 16);
    r.y = __uint_as_float((unsigned)u.y << 16);
    r.z = __uint_as_float((unsigned)u.z << 16);
    r.w = __uint_as_float((unsigned)u.w << 16);
    return r;
}

// One-time W transform: W[K][N] fp32 -> Wt_hi/Wt_lo[N][K] bf16 (hi + residual).
__global__ void k_wprep(const float* __restrict__ W, unsigned short* __restrict__ Wt_hi,
                        unsigned short* __restrict__ Wt_lo, int K, int N) {
    int id = blockIdx.x * blockDim.x + threadIdx.x;
    if (id < K * N) {
        int k = id / N, nn = id - k * N;         // coalesced read of W
        float f = W[id];
        unsigned short h = f2bf_rne(f);
        float hf = __uint_as_float((unsigned)h << 16);
        Wt_hi[(size_t)nn * K + k] = h;
        Wt_lo[(size_t)nn * K + k] = f2bf_rne(f - hf);
    }
}

// init: zero cnt; block 0 wave 0 also detects int64-vs-int32 edge layout.
__global__ void k_init(const int* __restrict__ e32, int* __restrict__ flag,
                       int* __restrict__ cnt, int n) {
    int i = blockIdx.x * blockDim.x + threadIdx.x;
    if (i < n) cnt[i] = 0;
    if (blockIdx.x == 0 && threadIdx.x < 64) {
        int v = e32[2 * threadIdx.x + 1];
        unsigned long long ball = __ballot(v == 0);
        if (threadIdx.x == 0) flag[0] = (ball == ~0ull) ? 1 : 0;
    }
}

__device__ __forceinline__ int edge_at(const int* __restrict__ e32, long long idx, int is64) {
    return is64 ? e32[2 * idx] : e32[(int)idx];
}

__global__ void k_count(const int* __restrict__ e32, const int* __restrict__ flag,
                        int* __restrict__ cnt, int E) {
    int is64 = flag[0];
    int e = blockIdx.x * blockDim.x + threadIdx.x;
    if (e < E) {
        int d = edge_at(e32, (long long)E + e, is64);   // dst row = second half
        atomicAdd(&cnt[d], 1);
    }
}

#define SCB 256            // scan block threads
#define SCE 8              // elements per thread
#define SCTILE (SCB * SCE) // 2048 elements per block

__global__ __launch_bounds__(SCB) void k_scan1(const int* __restrict__ cnt,
                                               int* __restrict__ blksum, int n) {
    __shared__ int red[SCB];
    int t = threadIdx.x;
    int base = blockIdx.x * SCTILE + t * SCE;
    int s = 0;
    if (base + SCE <= n) {
        int4 a = *reinterpret_cast<const int4*>(&cnt[base]);
        int4 b = *reinterpret_cast<const int4*>(&cnt[base + 4]);
        s = a.x + a.y + a.z + a.w + b.x + b.y + b.z + b.w;
    } else {
        for (int i = 0; i < SCE; ++i) { int idx = base + i; if (idx < n) s += cnt[idx]; }
    }
    red[t] = s;
    __syncthreads();
    for (int off = SCB / 2; off > 0; off >>= 1) {
        if (t < off) red[t] += red[t + off];
        __syncthreads();
    }
    if (t == 0) blksum[blockIdx.x] = red[0];
}

__global__ __launch_bounds__(SCB) void k_scan2(int* __restrict__ blksum, int nb) {
    __shared__ int red[SCB];
    int t = threadIdx.x;
    int v = (t < nb) ? blksum[t] : 0;
    red[t] = v;
    __syncthreads();
    for (int off = 1; off < SCB; off <<= 1) {          // Hillis-Steele inclusive
        int x = (t >= off) ? red[t - off] : 0;
        __syncthreads();
        red[t] += x;
        __syncthreads();
    }
    if (t < nb) blksum[t] = red[t] - v;                // exclusive, in place
}

// scan3: rowptr + fused dinv + cursor zero.
__global__ __launch_bounds__(SCB) void k_scan3(const int* __restrict__ cnt,
                                               const int* __restrict__ blksum,
                                               int* __restrict__ rowptr,
                                               float* __restrict__ dinv,
                                               int* __restrict__ cursor,
                                               int n, int E) {
    __shared__ int red[SCB];
    int t = threadIdx.x;
    int base = blockIdx.x * SCTILE + t * SCE;
    int v[SCE];
    int s = 0;
    if (base + SCE <= n) {
        int4 a = *reinterpret_cast<const int4*>(&cnt[base]);
        int4 b = *reinterpret_cast<const int4*>(&cnt[base + 4]);
        v[0] = a.x; v[1] = a.y; v[2] = a.z; v[3] = a.w;
        v[4] = b.x; v[5] = b.y; v[6] = b.z; v[7] = b.w;
        s = v[0] + v[1] + v[2] + v[3] + v[4] + v[5] + v[6] + v[7];
    } else {
        for (int i = 0; i < SCE; ++i) {
            int idx = base + i;
            v[i] = (idx < n) ? cnt[idx] : 0;
            s += v[i];
        }
    }
    red[t] = s;
    __syncthreads();
    for (int off = 1; off < SCB; off <<= 1) {
        int x = (t >= off) ? red[t - off] : 0;
        __syncthreads();
        red[t] += x;
        __syncthreads();
    }
    int run = red[t] - s + blksum[blockIdx.x];
    #pragma unroll
    for (int i = 0; i < SCE; ++i) {
        int idx = base + i;
        if (idx < n) {
            rowptr[idx] = run;
            dinv[idx]   = rsqrtf(1.0f + (float)v[i]);  // self-loop included
            cursor[idx] = 0;
            run += v[i];
        }
    }
    if (blockIdx.x == 0 && t == 0) rowptr[n] = E;
}

// CSR fill: esrc[pos] = src   (dinv folded into table rows, no per-edge norm).
__global__ void k_fill(const int* __restrict__ e32, const int* __restrict__ flag,
                       const int* __restrict__ rowptr, int* __restrict__ cursor,
                       int* __restrict__ esrc, int E) {
    int is64 = flag[0];
    int e = blockIdx.x * blockDim.x + threadIdx.x;
    if (e < E) {
        int s = edge_at(e32, e, is64);
        int d = edge_at(e32, (long long)E + e, is64);
        int pos = rowptr[d] + atomicAdd(&cursor[d], 1);
        esrc[pos] = s;
    }
}

// Split-bf16 MFMA GEMM:  Hb[n][N] (bf16) = dinv ⊙ (A @ W).   A row-major fp32.
// BM=64, 4 waves; wave w owns rows w*16..w*16+15 x all N cols.
// m89-verified 16x16x32 layouts: a[j]=A[l&15][(l>>4)*8+j], b[j]=B[(l>>4)*8+j][l&15],
// d[i]=D[(l>>4)*4+i][l&15].
template<int K, int N>
__global__ __launch_bounds__(256) void k_gemm_mfma(const float* __restrict__ A,
        const unsigned short* __restrict__ Wt_hi, const unsigned short* __restrict__ Wt_lo,
        const float* __restrict__ dinv, unsigned short* __restrict__ Hb, int n) {
    constexpr int NT  = N / 16;     // n-tiles per wave
    constexpr int LDA = 40;         // padded LDS row stride in bf16 (80 B, <=2-way conflicts)
    __shared__ unsigned short Ah[64 * LDA], Al[64 * LDA];
    __shared__ unsigned short Wh[N * LDA],  Wl[N * LDA];
    int t = threadIdx.x;
    int w = t >> 6, l = t & 63;
    int row0 = blockIdx.x * 64;
    int lrow = l & 15, lk = (l >> 4) * 8;
    f32x4 acc[NT];
    #pragma unroll
    for (int i = 0; i < NT; ++i) acc[i] = (f32x4){0.f, 0.f, 0.f, 0.f};

    for (int k0 = 0; k0 < K; k0 += 32) {
        {   // stage A tile [64][32] fp32 -> hi/lo bf16; thread t: row t>>2, k (t&3)*8
            int r = t >> 2, kk = (t & 3) * 8;
            int grow = row0 + r;
            float v[8] = {0.f, 0.f, 0.f, 0.f, 0.f, 0.f, 0.f, 0.f};
            if (grow < n) {
                float4 x0 = *reinterpret_cast<const float4*>(&A[(size_t)grow * K + k0 + kk]);
                float4 x1 = *reinterpret_cast<const float4*>(&A[(size_t)grow * K + k0 + kk + 4]);
                v[0] = x0.x; v[1] = x0.y; v[2] = x0.z; v[3] = x0.w;
                v[4] = x1.x; v[5] = x1.y; v[6] = x1.z; v[7] = x1.w;
            }
            unsigned short h8[8], l8[8];
            #pragma unroll
            for (int i = 0; i < 8; ++i) {
                unsigned short h = f2bf_rne(v[i]);
                h8[i] = h;
                l8[i] = f2bf_rne(v[i] - __uint_as_float((unsigned)h << 16));
            }
            *reinterpret_cast<bf16x8*>(&Ah[r * LDA + kk]) = *reinterpret_cast<const bf16x8*>(h8);
            *reinterpret_cast<bf16x8*>(&Al[r * LDA + kk]) = *reinterpret_cast<const bf16x8*>(l8);
        }
        // stage W k-slice: Wt[nn][k0..k0+32] -> Wh/Wl, 16B chunks
        for (int c = t; c < N * 4; c += 256) {
            int nn = c >> 2, part = (c & 3) * 8;
            *reinterpret_cast<bf16x8*>(&Wh[nn * LDA + part]) =
                *reinterpret_cast<const bf16x8*>(&Wt_hi[(size_t)nn * K + k0 + part]);
            *reinterpret_cast<bf16x8*>(&Wl[nn * LDA + part]) =
                *reinterpret_cast<const bf16x8*>(&Wt_lo[(size_t)nn * K + k0 + part]);
        }
        __syncthreads();
        bf16x8 ah = *reinterpret_cast<const bf16x8*>(&Ah[(w * 16 + lrow) * LDA + lk]);
        bf16x8 al = *reinterpret_cast<const bf16x8*>(&Al[(w * 16 + lrow) * LDA + lk]);
        #pragma unroll
        for (int tt = 0; tt < NT; ++tt) {
            bf16x8 bh = *reinterpret_cast<const bf16x8*>(&Wh[(tt * 16 + lrow) * LDA + lk]);
            bf16x8 bl = *reinterpret_cast<const bf16x8*>(&Wl[(tt * 16 + lrow) * LDA + lk]);
            acc[tt] = __builtin_amdgcn_mfma_f32_16x16x32_bf16(ah, bh, acc[tt], 0, 0, 0);
            acc[tt] = __builtin_amdgcn_mfma_f32_16x16x32_bf16(al, bh, acc[tt], 0, 0, 0);
            acc[tt] = __builtin_amdgcn_mfma_f32_16x16x32_bf16(ah, bl, acc[tt], 0, 0, 0);
        }
        __syncthreads();
    }
    #pragma unroll
    for (int i = 0; i < 4; ++i) {
        int grow = row0 + w * 16 + (l >> 4) * 4 + i;
        if (grow < n) {
            float dv = dinv[grow];
            #pragma unroll
            for (int tt = 0; tt < NT; ++tt)
                Hb[(size_t)grow * N + tt * 16 + lrow] = f2bf_rne(acc[tt][i] * dv);
        }
    }
}

// Aggregation over bf16 table.  LPN lanes per node (NF = LPN*4 features),
// whole-row gathers (LPN*8 B), 8-deep edge unroll for MLP, fp32 output.
// out = dinv[i]*(Σ_{s∈N(i)} t[s] + t[i]) + bias   (t already dinv-scaled)
template<int LPN, bool RELU>
__global__ __launch_bounds__(256) void k_aggb(const unsigned short* __restrict__ Hb,
                                              const float* __restrict__ dinv,
                                              const int* __restrict__ rowptr,
                                              const int* __restrict__ esrc,
                                              const float* __restrict__ bias,
                                              float* __restrict__ O, int n) {
    constexpr int NF = LPN * 4;
    int grp  = threadIdx.x / LPN;
    int lane = threadIdx.x % LPN;
    int node = blockIdx.x * (256 / LPN) + grp;
    if (node >= n) return;
    int f = lane * 4;
    float dn = dinv[node];
    float4 acc = bf4f(*reinterpret_cast<const ushort4*>(&Hb[(size_t)node * NF + f]));
    int lo = rowptr[node], hi = rowptr[node + 1];
    int e = lo;
    for (; e + 8 <= hi; e += 8) {            // 8 row-gathers in flight
        int s0 = esrc[e+0], s1 = esrc[e+1], s2 = esrc[e+2], s3 = esrc[e+3];
        int s4 = esrc[e+4], s5 = esrc[e+5], s6 = esrc[e+6], s7 = esrc[e+7];
        float4 v0 = bf4f(*reinterpret_cast<const ushort4*>(&Hb[(size_t)s0 * NF + f]));
        float4 v1 = bf4f(*reinterpret_cast<const ushort4*>(&Hb[(size_t)s1 * NF + f]));
        float4 v2 = bf4f(*reinterpret_cast<const ushort4*>(&Hb[(size_t)s2 * NF + f]));
        float4 v3 = bf4f(*reinterpret_cast<const ushort4*>(&Hb[(size_t)s3 * NF + f]));
        float4 v4 = bf4f(*reinterpret_cast<const ushort4*>(&Hb[(size_t)s4 * NF + f]));
        float4 v5 = bf4f(*reinterpret_cast<const ushort4*>(&Hb[(size_t)s5 * NF + f]));
        float4 v6 = bf4f(*reinterpret_cast<const ushort4*>(&Hb[(size_t)s6 * NF + f]));
        float4 v7 = bf4f(*reinterpret_cast<const ushort4*>(&Hb[(size_t)s7 * NF + f]));
        acc.x += ((v0.x + v1.x) + (v2.x + v3.x)) + ((v4.x + v5.x) + (v6.x + v7.x));
        acc.y += ((v0.y + v1.y) + (v2.y + v3.y)) + ((v4.y + v5.y) + (v6.y + v7.y));
        acc.z += ((v0.z + v1.z) + (v2.z + v3.z)) + ((v4.z + v5.z) + (v6.z + v7.z));
        acc.w += ((v0.w + v1.w) + (v2.w + v3.w)) + ((v4.w + v5.w) + (v6.w + v7.w));
    }
    for (; e < hi; ++e) {
        float4 v = bf4f(*reinterpret_cast<const ushort4*>(&Hb[(size_t)esrc[e] * NF + f]));
        acc.x += v.x; acc.y += v.y; acc.z += v.z; acc.w += v.w;
    }
    float4 bv = *reinterpret_cast<const float4*>(&bias[f]);
    acc.x = acc.x * dn + bv.x;
    acc.y = acc.y * dn + bv.y;
    acc.z = acc.z * dn + bv.z;
    acc.w = acc.w * dn + bv.w;
    if (RELU) {
        acc.x = fmaxf(acc.x, 0.f); acc.y = fmaxf(acc.y, 0.f);
        acc.z = fmaxf(acc.z, 0.f); acc.w = fmaxf(acc.w, 0.f);
    }
    *reinterpret_cast<float4*>(&O[(size_t)node * NF + f]) = acc;
}

extern "C" void kernel_launch(void* const* d_in, const int* in_sizes, int n_in,
                              void* d_out, int out_size, void* d_ws, size_t ws_size,
                              hipStream_t stream) {
    const float* x   = (const float*)d_in[0];
    const int*   e32 = (const int*)d_in[1];
    const float* W1  = (const float*)d_in[2];
    const float* b1  = (const float*)d_in[3];
    const float* W2  = (const float*)d_in[4];
    const float* b2  = (const float*)d_in[5];
    float* out = (float*)d_out;

    const int HID  = in_sizes[3];           // 128
    const int FIN  = in_sizes[2] / HID;     // 256
    const int N    = in_sizes[0] / FIN;     // 50000
    const int E    = in_sizes[1] / 2;       // 800000
    const int OUT  = in_sizes[5];           // 64
    (void)n_in; (void)out_size; (void)ws_size;

    char* ws = (char*)d_ws;
    size_t off = 0;
    auto take = [&](size_t bytes) -> void* {
        void* p = ws + off;
        off += (bytes + 255) & ~(size_t)255;
        return p;
    };
    int*            flag   = (int*)            take(4);
    float*          dinv   = (float*)          take((size_t)N * 4);
    int*            cnt    = (int*)            take((size_t)N * 4);
    int*            rowptr = (int*)            take((size_t)(N + 1) * 4);
    int*            blksum = (int*)            take((size_t)SCB * 4);
    unsigned short* w1h    = (unsigned short*) take((size_t)FIN * HID * 2);
    unsigned short* w1l    = (unsigned short*) take((size_t)FIN * HID * 2);
    unsigned short* w2h    = (unsigned short*) take((size_t)HID * OUT * 2);
    unsigned short* w2l    = (unsigned short*) take((size_t)HID * OUT * 2);
    int*            esrc   = (int*)            take((size_t)E * 4);
    unsigned short* h1b    = (unsigned short*) take((size_t)N * HID * 2);
    float*          agg1   = (float*)          take((size_t)N * HID * 4);
    unsigned short* h2b    = (unsigned short*) take((size_t)N * OUT * 2);

    int gN  = (N + 255) / 256;
    int gE  = (E + 255) / 256;
    int gS  = (N + SCTILE - 1) / SCTILE;    // 25 @ N=50000
    int gM  = (N + 63) / 64;                // 782
    int gW1 = (FIN * HID + 255) / 256;
    int gW2 = (HID * OUT + 255) / 256;
    int gA1 = (N + 7) / 8;                  // 8 nodes/block (32 lanes each)
    int gA2 = (N + 15) / 16;                // 16 nodes/block (16 lanes each)

    k_wprep <<<gW1, 256, 0, stream>>>(W1, w1h, w1l, FIN, HID);
    k_wprep <<<gW2, 256, 0, stream>>>(W2, w2h, w2l, HID, OUT);
    k_init  <<<gN,  256, 0, stream>>>(e32, flag, cnt, N);
    k_count <<<gE,  256, 0, stream>>>(e32, flag, cnt, E);
    k_scan1 <<<gS,  SCB, 0, stream>>>(cnt, blksum, N);
    k_scan2 <<<1,   SCB, 0, stream>>>(blksum, gS);
    k_scan3 <<<gS,  SCB, 0, stream>>>(cnt, blksum, rowptr, dinv, cnt, N, E);
    k_fill  <<<gE,  256, 0, stream>>>(e32, flag, rowptr, cnt, esrc, E);
    k_gemm_mfma<256, 128><<<gM, 256, 0, stream>>>(x, w1h, w1l, dinv, h1b, N);
    k_aggb<32, true> <<<gA1, 256, 0, stream>>>(h1b, dinv, rowptr, esrc, b1, agg1, N);
    k_gemm_mfma<128, 64> <<<gM, 256, 0, stream>>>(agg1, w2h, w2l, dinv, h2b, N);
    k_aggb<16, false><<<gA2, 256, 0, stream>>>(h2b, dinv, rowptr, esrc, b2, out, N);
}

// Round 10
// 238.590 us; speedup vs baseline: 1.7931x; 1.1362x over previous
//
#include <hip/hip_runtime.h>

// ---------------------------------------------------------------------------
// 2-layer GCN on MI355X.  Pipeline (12 launches):
//   wprep(W1) -> wprep(W2) -> init(+dtype detect) -> count(rank-pack) ->
//   scan1/2/3 -> fill (no atomic) -> GEMM1 (split-bf16 MFMA, xdinv, bf16 out)
//   -> AGG1 (bf16 gather, bf16 out) -> GEMM2 (bf16-A, 2 MFMA) -> AGG2 -> out
// Round-2: agg MLP (537->413).  Round-4: device scan (413->338).
// Round-5: split-bf16 MFMA GEMMs (338->303).  Round-8 FAILED: ft-tiled agg
//   (XCD L2 replication).  Round-9: bf16 gather tables (303->271).
// Round-10: k_fill was 45us latency-bound (atomic chain, VALU 0.8%).
//   k_count's atomicAdd return IS the edge rank -> pack dst|rank<<17 (u32,
//   coalesced); fill needs no atomic.  agg1 out bf16 -> gemm2 A is bf16
//   (2 MFMAs/tile, half the staging/read bytes).
// ---------------------------------------------------------------------------

typedef __attribute__((ext_vector_type(8))) short bf16x8;
typedef __attribute__((ext_vector_type(4))) float f32x4;

__device__ __forceinline__ unsigned short f2bf_rne(float f) {
    unsigned u = __float_as_uint(f);
    u = u + 0x7fffu + ((u >> 16) & 1u);          // round-to-nearest-even
    return (unsigned short)(u >> 16);
}

__device__ __forceinline__ float4 bf4f(ushort4 u) {
    float4 r;
    r.x = __uint_as_float((unsigned)u.x << 16);
    r.y = __uint_as_float((unsigned)u.y << 16);
    r.z = __uint_as_float((unsigned)u.z << 16);
    r.w = __uint_as_float((unsigned)u.w << 16);
    return r;
}

// One-time W transform: W[K][N] fp32 -> Wt_hi/Wt_lo[N][K] bf16 (hi + residual).
__global__ void k_wprep(const float* __restrict__ W, unsigned short* __restrict__ Wt_hi,
                        unsigned short* __restrict__ Wt_lo, int K, int N) {
    int id = blockIdx.x * blockDim.x + threadIdx.x;
    if (id < K * N) {
        int k = id / N, nn = id - k * N;         // coalesced read of W
        float f = W[id];
        unsigned short h = f2bf_rne(f);
        float hf = __uint_as_float((unsigned)h << 16);
        Wt_hi[(size_t)nn * K + k] = h;
        Wt_lo[(size_t)nn * K + k] = f2bf_rne(f - hf);
    }
}

// init: zero cnt; block 0 wave 0 also detects int64-vs-int32 edge layout.
__global__ void k_init(const int* __restrict__ e32, int* __restrict__ flag,
                       int* __restrict__ cnt, int n) {
    int i = blockIdx.x * blockDim.x + threadIdx.x;
    if (i < n) cnt[i] = 0;
    if (blockIdx.x == 0 && threadIdx.x < 64) {
        int v = e32[2 * threadIdx.x + 1];
        unsigned long long ball = __ballot(v == 0);
        if (threadIdx.x == 0) flag[0] = (ball == ~0ull) ? 1 : 0;
    }
}

__device__ __forceinline__ int edge_at(const int* __restrict__ e32, long long idx, int is64) {
    return is64 ? e32[2 * idx] : e32[(int)idx];
}

// count: deg atomic; the RETURN VALUE is this edge's rank within its dst.
// packed[e] = dst | rank<<17  (N < 2^17; Poisson-16 degrees << 2^15).
__global__ void k_count(const int* __restrict__ e32, const int* __restrict__ flag,
                        int* __restrict__ cnt, unsigned* __restrict__ packed, int E) {
    int is64 = flag[0];
    int e = blockIdx.x * blockDim.x + threadIdx.x;
    if (e < E) {
        int d = edge_at(e32, (long long)E + e, is64);   // dst row = second half
        int r = atomicAdd(&cnt[d], 1);
        packed[e] = (unsigned)d | ((unsigned)r << 17);
    }
}

#define SCB 256            // scan block threads
#define SCE 8              // elements per thread
#define SCTILE (SCB * SCE) // 2048 elements per block

__global__ __launch_bounds__(SCB) void k_scan1(const int* __restrict__ cnt,
                                               int* __restrict__ blksum, int n) {
    __shared__ int red[SCB];
    int t = threadIdx.x;
    int base = blockIdx.x * SCTILE + t * SCE;
    int s = 0;
    if (base + SCE <= n) {
        int4 a = *reinterpret_cast<const int4*>(&cnt[base]);
        int4 b = *reinterpret_cast<const int4*>(&cnt[base + 4]);
        s = a.x + a.y + a.z + a.w + b.x + b.y + b.z + b.w;
    } else {
        for (int i = 0; i < SCE; ++i) { int idx = base + i; if (idx < n) s += cnt[idx]; }
    }
    red[t] = s;
    __syncthreads();
    for (int off = SCB / 2; off > 0; off >>= 1) {
        if (t < off) red[t] += red[t + off];
        __syncthreads();
    }
    if (t == 0) blksum[blockIdx.x] = red[0];
}

__global__ __launch_bounds__(SCB) void k_scan2(int* __restrict__ blksum, int nb) {
    __shared__ int red[SCB];
    int t = threadIdx.x;
    int v = (t < nb) ? blksum[t] : 0;
    red[t] = v;
    __syncthreads();
    for (int off = 1; off < SCB; off <<= 1) {          // Hillis-Steele inclusive
        int x = (t >= off) ? red[t - off] : 0;
        __syncthreads();
        red[t] += x;
        __syncthreads();
    }
    if (t < nb) blksum[t] = red[t] - v;                // exclusive, in place
}

// scan3: rowptr + fused dinv  (no cursor needed any more).
__global__ __launch_bounds__(SCB) void k_scan3(const int* __restrict__ cnt,
                                               const int* __restrict__ blksum,
                                               int* __restrict__ rowptr,
                                               float* __restrict__ dinv,
                                               int n, int E) {
    __shared__ int red[SCB];
    int t = threadIdx.x;
    int base = blockIdx.x * SCTILE + t * SCE;
    int v[SCE];
    int s = 0;
    if (base + SCE <= n) {
        int4 a = *reinterpret_cast<const int4*>(&cnt[base]);
        int4 b = *reinterpret_cast<const int4*>(&cnt[base + 4]);
        v[0] = a.x; v[1] = a.y; v[2] = a.z; v[3] = a.w;
        v[4] = b.x; v[5] = b.y; v[6] = b.z; v[7] = b.w;
        s = v[0] + v[1] + v[2] + v[3] + v[4] + v[5] + v[6] + v[7];
    } else {
        for (int i = 0; i < SCE; ++i) {
            int idx = base + i;
            v[i] = (idx < n) ? cnt[idx] : 0;
            s += v[i];
        }
    }
    red[t] = s;
    __syncthreads();
    for (int off = 1; off < SCB; off <<= 1) {
        int x = (t >= off) ? red[t - off] : 0;
        __syncthreads();
        red[t] += x;
        __syncthreads();
    }
    int run = red[t] - s + blksum[blockIdx.x];
    #pragma unroll
    for (int i = 0; i < SCE; ++i) {
        int idx = base + i;
        if (idx < n) {
            rowptr[idx] = run;
            dinv[idx]   = rsqrtf(1.0f + (float)v[i]);  // self-loop included
            run += v[i];
        }
    }
    if (blockIdx.x == 0 && t == 0) rowptr[n] = E;
}

// CSR fill, atomic-free: pos = rowptr[dst] + rank (both from packed record).
__global__ void k_fill(const int* __restrict__ e32, const int* __restrict__ flag,
                       const int* __restrict__ rowptr, const unsigned* __restrict__ packed,
                       int* __restrict__ esrc, int E) {
    int is64 = flag[0];
    int e = blockIdx.x * blockDim.x + threadIdx.x;
    if (e < E) {
        int s = edge_at(e32, e, is64);
        unsigned p = packed[e];
        int d = (int)(p & 0x1FFFFu);
        int r = (int)(p >> 17);
        esrc[rowptr[d] + r] = s;
    }
}

// Split-bf16 MFMA GEMM (layer 1):  Hb[n][N] (bf16) = dinv ⊙ (A @ W), A fp32.
// BM=64, 4 waves; wave w owns rows w*16..w*16+15 x all N cols.
// m89-verified 16x16x32 layouts: a[j]=A[l&15][(l>>4)*8+j], b[j]=B[(l>>4)*8+j][l&15],
// d[i]=D[(l>>4)*4+i][l&15].
template<int K, int N>
__global__ __launch_bounds__(256) void k_gemm_mfma(const float* __restrict__ A,
        const unsigned short* __restrict__ Wt_hi, const unsigned short* __restrict__ Wt_lo,
        const float* __restrict__ dinv, unsigned short* __restrict__ Hb, int n) {
    constexpr int NT  = N / 16;     // n-tiles per wave
    constexpr int LDA = 40;         // padded LDS row stride in bf16 (80 B, <=2-way conflicts)
    __shared__ unsigned short Ah[64 * LDA], Al[64 * LDA];
    __shared__ unsigned short Wh[N * LDA],  Wl[N * LDA];
    int t = threadIdx.x;
    int w = t >> 6, l = t & 63;
    int row0 = blockIdx.x * 64;
    int lrow = l & 15, lk = (l >> 4) * 8;
    f32x4 acc[NT];
    #pragma unroll
    for (int i = 0; i < NT; ++i) acc[i] = (f32x4){0.f, 0.f, 0.f, 0.f};

    for (int k0 = 0; k0 < K; k0 += 32) {
        {   // stage A tile [64][32] fp32 -> hi/lo bf16; thread t: row t>>2, k (t&3)*8
            int r = t >> 2, kk = (t & 3) * 8;
            int grow = row0 + r;
            float v[8] = {0.f, 0.f, 0.f, 0.f, 0.f, 0.f, 0.f, 0.f};
            if (grow < n) {
                float4 x0 = *reinterpret_cast<const float4*>(&A[(size_t)grow * K + k0 + kk]);
                float4 x1 = *reinterpret_cast<const float4*>(&A[(size_t)grow * K + k0 + kk + 4]);
                v[0] = x0.x; v[1] = x0.y; v[2] = x0.z; v[3] = x0.w;
                v[4] = x1.x; v[5] = x1.y; v[6] = x1.z; v[7] = x1.w;
            }
            unsigned short h8[8], l8[8];
            #pragma unroll
            for (int i = 0; i < 8; ++i) {
                unsigned short h = f2bf_rne(v[i]);
                h8[i] = h;
                l8[i] = f2bf_rne(v[i] - __uint_as_float((unsigned)h << 16));
            }
            *reinterpret_cast<bf16x8*>(&Ah[r * LDA + kk]) = *reinterpret_cast<const bf16x8*>(h8);
            *reinterpret_cast<bf16x8*>(&Al[r * LDA + kk]) = *reinterpret_cast<const bf16x8*>(l8);
        }
        // stage W k-slice: Wt[nn][k0..k0+32] -> Wh/Wl, 16B chunks
        for (int c = t; c < N * 4; c += 256) {
            int nn = c >> 2, part = (c & 3) * 8;
            *reinterpret_cast<bf16x8*>(&Wh[nn * LDA + part]) =
                *reinterpret_cast<const bf16x8*>(&Wt_hi[(size_t)nn * K + k0 + part]);
            *reinterpret_cast<bf16x8*>(&Wl[nn * LDA + part]) =
                *reinterpret_cast<const bf16x8*>(&Wt_lo[(size_t)nn * K + k0 + part]);
        }
        __syncthreads();
        bf16x8 ah = *reinterpret_cast<const bf16x8*>(&Ah[(w * 16 + lrow) * LDA + lk]);
        bf16x8 al = *reinterpret_cast<const bf16x8*>(&Al[(w * 16 + lrow) * LDA + lk]);
        #pragma unroll
        for (int tt = 0; tt < NT; ++tt) {
            bf16x8 bh = *reinterpret_cast<const bf16x8*>(&Wh[(tt * 16 + lrow) * LDA + lk]);
            bf16x8 bl = *reinterpret_cast<const bf16x8*>(&Wl[(tt * 16 + lrow) * LDA + lk]);
            acc[tt] = __builtin_amdgcn_mfma_f32_16x16x32_bf16(ah, bh, acc[tt], 0, 0, 0);
            acc[tt] = __builtin_amdgcn_mfma_f32_16x16x32_bf16(al, bh, acc[tt], 0, 0, 0);
            acc[tt] = __builtin_amdgcn_mfma_f32_16x16x32_bf16(ah, bl, acc[tt], 0, 0, 0);
        }
        __syncthreads();
    }
    #pragma unroll
    for (int i = 0; i < 4; ++i) {
        int grow = row0 + w * 16 + (l >> 4) * 4 + i;
        if (grow < n) {
            float dv = dinv[grow];
            #pragma unroll
            for (int tt = 0; tt < NT; ++tt)
                Hb[(size_t)grow * N + tt * 16 + lrow] = f2bf_rne(acc[tt][i] * dv);
        }
    }
}

// Layer-2 GEMM: A already bf16 [n][K] (no lo term) -> 2 MFMAs per tile.
template<int K, int N>
__global__ __launch_bounds__(256) void k_gemm_bf16A(const unsigned short* __restrict__ A,
        const unsigned short* __restrict__ Wt_hi, const unsigned short* __restrict__ Wt_lo,
        const float* __restrict__ dinv, unsigned short* __restrict__ Hb, int n) {
    constexpr int NT  = N / 16;
    constexpr int LDA = 40;
    __shared__ unsigned short Ah[64 * LDA];
    __shared__ unsigned short Wh[N * LDA], Wl[N * LDA];
    int t = threadIdx.x;
    int w = t >> 6, l = t & 63;
    int row0 = blockIdx.x * 64;
    int lrow = l & 15, lk = (l >> 4) * 8;
    f32x4 acc[NT];
    #pragma unroll
    for (int i = 0; i < NT; ++i) acc[i] = (f32x4){0.f, 0.f, 0.f, 0.f};

    for (int k0 = 0; k0 < K; k0 += 32) {
        {   // stage A tile [64][32] bf16: thread t: row t>>2, k (t&3)*8 (16B load)
            int r = t >> 2, kk = (t & 3) * 8;
            int grow = row0 + r;
            bf16x8 v = {};
            if (grow < n) v = *reinterpret_cast<const bf16x8*>(&A[(size_t)grow * K + k0 + kk]);
            *reinterpret_cast<bf16x8*>(&Ah[r * LDA + kk]) = v;
        }
        for (int c = t; c < N * 4; c += 256) {
            int nn = c >> 2, part = (c & 3) * 8;
            *reinterpret_cast<bf16x8*>(&Wh[nn * LDA + part]) =
                *reinterpret_cast<const bf16x8*>(&Wt_hi[(size_t)nn * K + k0 + part]);
            *reinterpret_cast<bf16x8*>(&Wl[nn * LDA + part]) =
                *reinterpret_cast<const bf16x8*>(&Wt_lo[(size_t)nn * K + k0 + part]);
        }
        __syncthreads();
        bf16x8 ah = *reinterpret_cast<const bf16x8*>(&Ah[(w * 16 + lrow) * LDA + lk]);
        #pragma unroll
        for (int tt = 0; tt < NT; ++tt) {
            bf16x8 bh = *reinterpret_cast<const bf16x8*>(&Wh[(tt * 16 + lrow) * LDA + lk]);
            bf16x8 bl = *reinterpret_cast<const bf16x8*>(&Wl[(tt * 16 + lrow) * LDA + lk]);
            acc[tt] = __builtin_amdgcn_mfma_f32_16x16x32_bf16(ah, bh, acc[tt], 0, 0, 0);
            acc[tt] = __builtin_amdgcn_mfma_f32_16x16x32_bf16(ah, bl, acc[tt], 0, 0, 0);
        }
        __syncthreads();
    }
    #pragma unroll
    for (int i = 0; i < 4; ++i) {
        int grow = row0 + w * 16 + (l >> 4) * 4 + i;
        if (grow < n) {
            float dv = dinv[grow];
            #pragma unroll
            for (int tt = 0; tt < NT; ++tt)
                Hb[(size_t)grow * N + tt * 16 + lrow] = f2bf_rne(acc[tt][i] * dv);
        }
    }
}

// Aggregation over bf16 table.  LPN lanes per node (NF = LPN*4 features),
// whole-row gathers (LPN*8 B), 8-deep edge unroll for MLP.
// out = dinv[i]*(Σ_{s∈N(i)} t[s] + t[i]) + bias   (t already dinv-scaled)
template<int LPN, bool RELU, bool OUT_BF16>
__global__ __launch_bounds__(256) void k_aggb(const unsigned short* __restrict__ Hb,
                                              const float* __restrict__ dinv,
                                              const int* __restrict__ rowptr,
                                              const int* __restrict__ esrc,
                                              const float* __restrict__ bias,
                                              void* __restrict__ Optr, int n) {
    constexpr int NF = LPN * 4;
    int grp  = threadIdx.x / LPN;
    int lane = threadIdx.x % LPN;
    int node = blockIdx.x * (256 / LPN) + grp;
    if (node >= n) return;
    int f = lane * 4;
    float dn = dinv[node];
    float4 acc = bf4f(*reinterpret_cast<const ushort4*>(&Hb[(size_t)node * NF + f]));
    int lo = rowptr[node], hi = rowptr[node + 1];
    int e = lo;
    for (; e + 8 <= hi; e += 8) {            // 8 row-gathers in flight
        int s0 = esrc[e+0], s1 = esrc[e+1], s2 = esrc[e+2], s3 = esrc[e+3];
        int s4 = esrc[e+4], s5 = esrc[e+5], s6 = esrc[e+6], s7 = esrc[e+7];
        float4 v0 = bf4f(*reinterpret_cast<const ushort4*>(&Hb[(size_t)s0 * NF + f]));
        float4 v1 = bf4f(*reinterpret_cast<const ushort4*>(&Hb[(size_t)s1 * NF + f]));
        float4 v2 = bf4f(*reinterpret_cast<const ushort4*>(&Hb[(size_t)s2 * NF + f]));
        float4 v3 = bf4f(*reinterpret_cast<const ushort4*>(&Hb[(size_t)s3 * NF + f]));
        float4 v4 = bf4f(*reinterpret_cast<const ushort4*>(&Hb[(size_t)s4 * NF + f]));
        float4 v5 = bf4f(*reinterpret_cast<const ushort4*>(&Hb[(size_t)s5 * NF + f]));
        float4 v6 = bf4f(*reinterpret_cast<const ushort4*>(&Hb[(size_t)s6 * NF + f]));
        float4 v7 = bf4f(*reinterpret_cast<const ushort4*>(&Hb[(size_t)s7 * NF + f]));
        acc.x += ((v0.x + v1.x) + (v2.x + v3.x)) + ((v4.x + v5.x) + (v6.x + v7.x));
        acc.y += ((v0.y + v1.y) + (v2.y + v3.y)) + ((v4.y + v5.y) + (v6.y + v7.y));
        acc.z += ((v0.z + v1.z) + (v2.z + v3.z)) + ((v4.z + v5.z) + (v6.z + v7.z));
        acc.w += ((v0.w + v1.w) + (v2.w + v3.w)) + ((v4.w + v5.w) + (v6.w + v7.w));
    }
    for (; e < hi; ++e) {
        float4 v = bf4f(*reinterpret_cast<const ushort4*>(&Hb[(size_t)esrc[e] * NF + f]));
        acc.x += v.x; acc.y += v.y; acc.z += v.z; acc.w += v.w;
    }
    float4 bv = *reinterpret_cast<const float4*>(&bias[f]);
    acc.x = acc.x * dn + bv.x;
    acc.y = acc.y * dn + bv.y;
    acc.z = acc.z * dn + bv.z;
    acc.w = acc.w * dn + bv.w;
    if (RELU) {
        acc.x = fmaxf(acc.x, 0.f); acc.y = fmaxf(acc.y, 0.f);
        acc.z = fmaxf(acc.z, 0.f); acc.w = fmaxf(acc.w, 0.f);
    }
    if (OUT_BF16) {
        ushort4 o = { f2bf_rne(acc.x), f2bf_rne(acc.y), f2bf_rne(acc.z), f2bf_rne(acc.w) };
        *reinterpret_cast<ushort4*>(&((unsigned short*)Optr)[(size_t)node * NF + f]) = o;
    } else {
        *reinterpret_cast<float4*>(&((float*)Optr)[(size_t)node * NF + f]) = acc;
    }
}

extern "C" void kernel_launch(void* const* d_in, const int* in_sizes, int n_in,
                              void* d_out, int out_size, void* d_ws, size_t ws_size,
                              hipStream_t stream) {
    const float* x   = (const float*)d_in[0];
    const int*   e32 = (const int*)d_in[1];
    const float* W1  = (const float*)d_in[2];
    const float* b1  = (const float*)d_in[3];
    const float* W2  = (const float*)d_in[4];
    const float* b2  = (const float*)d_in[5];
    float* out = (float*)d_out;

    const int HID  = in_sizes[3];           // 128
    const int FIN  = in_sizes[2] / HID;     // 256
    const int N    = in_sizes[0] / FIN;     // 50000
    const int E    = in_sizes[1] / 2;       // 800000
    const int OUT  = in_sizes[5];           // 64
    (void)n_in; (void)out_size; (void)ws_size;

    char* ws = (char*)d_ws;
    size_t off = 0;
    auto take = [&](size_t bytes) -> void* {
        void* p = ws + off;
        off += (bytes + 255) & ~(size_t)255;
        return p;
    };
    int*            flag   = (int*)            take(4);
    float*          dinv   = (float*)          take((size_t)N * 4);
    int*            cnt    = (int*)            take((size_t)N * 4);
    int*            rowptr = (int*)            take((size_t)(N + 1) * 4);
    int*            blksum = (int*)            take((size_t)SCB * 4);
    unsigned short* w1h    = (unsigned short*) take((size_t)FIN * HID * 2);
    unsigned short* w1l    = (unsigned short*) take((size_t)FIN * HID * 2);
    unsigned short* w2h    = (unsigned short*) take((size_t)HID * OUT * 2);
    unsigned short* w2l    = (unsigned short*) take((size_t)HID * OUT * 2);
    unsigned*       packed = (unsigned*)       take((size_t)E * 4);
    int*            esrc   = (int*)            take((size_t)E * 4);
    unsigned short* h1b    = (unsigned short*) take((size_t)N * HID * 2);
    unsigned short* agg1b  = (unsigned short*) take((size_t)N * HID * 2);
    unsigned short* h2b    = (unsigned short*) take((size_t)N * OUT * 2);

    int gN  = (N + 255) / 256;
    int gE  = (E + 255) / 256;
    int gS  = (N + SCTILE - 1) / SCTILE;    // 25 @ N=50000
    int gM  = (N + 63) / 64;                // 782
    int gW1 = (FIN * HID + 255) / 256;
    int gW2 = (HID * OUT + 255) / 256;
    int gA1 = (N + 7) / 8;                  // 8 nodes/block (32 lanes each)
    int gA2 = (N + 15) / 16;                // 16 nodes/block (16 lanes each)

    k_wprep <<<gW1, 256, 0, stream>>>(W1, w1h, w1l, FIN, HID);
    k_wprep <<<gW2, 256, 0, stream>>>(W2, w2h, w2l, HID, OUT);
    k_init  <<<gN,  256, 0, stream>>>(e32, flag, cnt, N);
    k_count <<<gE,  256, 0, stream>>>(e32, flag, cnt, packed, E);
    k_scan1 <<<gS,  SCB, 0, stream>>>(cnt, blksum, N);
    k_scan2 <<<1,   SCB, 0, stream>>>(blksum, gS);
    k_scan3 <<<gS,  SCB, 0, stream>>>(cnt, blksum, rowptr, dinv, N, E);
    k_fill  <<<gE,  256, 0, stream>>>(e32, flag, rowptr, packed, esrc, E);
    k_gemm_mfma<256, 128><<<gM, 256, 0, stream>>>(x, w1h, w1l, dinv, h1b, N);
    k_aggb<32, true,  true> <<<gA1, 256, 0, stream>>>(h1b, dinv, rowptr, esrc, b1, agg1b, N);
    k_gemm_bf16A<128, 64><<<gM, 256, 0, stream>>>(agg1b, w2h, w2l, dinv, h2b, N);
    k_aggb<16, false, false><<<gA2, 256, 0, stream>>>(h2b, dinv, rowptr, esrc, b2, out, N);
}